// Round 2
// baseline (2746.552 us; speedup 1.0000x reference)
//
#include <hip/hip_runtime.h>
#include <math.h>

#define B_ 512
#define T_ 128
#define D_ 512
#define O_ 10

// ---------------- GEMM1 + fused BN partial stats ----------------
#define BM 128
#define BN 128
#define BK 16
#define LR 17   // LDS row stride: ty-stride 8*17=136 ≡ 8 banks (conflict-free A);
                // interleaved cols give tx-stride 17 banks (odd → ~conflict-free W)

__global__ __launch_bounds__(256, 2)
void gemm1_kernel(const float* __restrict__ data, const float* __restrict__ drop,
                  const float* __restrict__ W1, const float* __restrict__ b1,
                  float* __restrict__ hbuf, double* __restrict__ pSum,
                  double* __restrict__ pSq, int t0, int Tc, int numX)
{
    __shared__ float As[2][BM * LR];
    __shared__ float Ws[2][BN * LR];

    const int tid = threadIdx.x;
    const int bid = blockIdx.x;

    // XCD swizzle: put the 4 d-tiles sharing one A-slab on the same XCD.
    int g, yy;
    if (numX & 7) { g = bid >> 2; yy = bid & 3; }
    else {
        const int xcd = bid & 7;
        const int rest = bid >> 3;
        yy = rest & 3;
        g = (rest >> 2) * 8 + xcd;
    }
    const int R = g * BM;          // chunk-row base (tc*512 + b_base)
    const int tc = R >> 9;
    const int b_base = R & 511;
    const int t = t0 + tc;
    const int d0 = yy * BN;

    const int tx = tid & 15;       // col group: cols tx + 16*j
    const int ty = tid >> 4;       // row group: rows ty*8 + i

    float acc[8][8];
#pragma unroll
    for (int i = 0; i < 8; ++i)
#pragma unroll
        for (int j = 0; j < 8; ++j) acc[i][j] = 0.f;

    const int lm0 = tid >> 2;          // 0..63
    const int lk0 = (tid & 3) * 4;     // 0,4,8,12
    const float* dataRow = data + ((size_t)b_base * T_ + t) * D_;
    const float* dropRow = drop + ((size_t)t * B_ + b_base) * D_;
    const float* WRow    = W1 + (size_t)d0 * D_;

    float4 avA, avB, wvA, wvB;

#define LOAD_TILE(K0)                                                            \
    {                                                                            \
        const int m0 = lm0, m1 = lm0 + 64;                                       \
        float4 dv0 = *(const float4*)(dataRow + (size_t)m0 * T_ * D_ + (K0) + lk0); \
        float4 mv0 = *(const float4*)(dropRow + (size_t)m0 * D_ + (K0) + lk0);   \
        avA.x = dv0.x * mv0.x; avA.y = dv0.y * mv0.y;                            \
        avA.z = dv0.z * mv0.z; avA.w = dv0.w * mv0.w;                            \
        float4 dv1 = *(const float4*)(dataRow + (size_t)m1 * T_ * D_ + (K0) + lk0); \
        float4 mv1 = *(const float4*)(dropRow + (size_t)m1 * D_ + (K0) + lk0);   \
        avB.x = dv1.x * mv1.x; avB.y = dv1.y * mv1.y;                            \
        avB.z = dv1.z * mv1.z; avB.w = dv1.w * mv1.w;                            \
        wvA = *(const float4*)(WRow + (size_t)m0 * D_ + (K0) + lk0);             \
        wvB = *(const float4*)(WRow + (size_t)m1 * D_ + (K0) + lk0);             \
    }

#define STORE_TILE(BUF)                                                          \
    {                                                                            \
        *(float4*)(&As[BUF][lm0 * LR + lk0]) = avA;                              \
        *(float4*)(&As[BUF][(lm0 + 64) * LR + lk0]) = avB;                       \
        *(float4*)(&Ws[BUF][lm0 * LR + lk0]) = wvA;                              \
        *(float4*)(&Ws[BUF][(lm0 + 64) * LR + lk0]) = wvB;                       \
    }

    LOAD_TILE(0)
    STORE_TILE(0)
    __syncthreads();

    int cur = 0;
    for (int k0 = 0; k0 < D_; k0 += BK) {
        const bool hasNext = (k0 + BK) < D_;
        if (hasNext) LOAD_TILE(k0 + BK)

#pragma unroll
        for (int kk = 0; kk < BK; kk += 4) {
            float4 a[8], w[8];
#pragma unroll
            for (int i = 0; i < 8; ++i)
                a[i] = *(const float4*)(&As[cur][(ty * 8 + i) * LR + kk]);
#pragma unroll
            for (int j = 0; j < 8; ++j)
                w[j] = *(const float4*)(&Ws[cur][(tx + 16 * j) * LR + kk]);
#pragma unroll
            for (int i = 0; i < 8; ++i)
#pragma unroll
                for (int j = 0; j < 8; ++j) {
                    acc[i][j] = fmaf(a[i].x, w[j].x, acc[i][j]);
                    acc[i][j] = fmaf(a[i].y, w[j].y, acc[i][j]);
                    acc[i][j] = fmaf(a[i].z, w[j].z, acc[i][j]);
                    acc[i][j] = fmaf(a[i].w, w[j].w, acc[i][j]);
                }
        }

        if (hasNext) STORE_TILE(cur ^ 1)
        __syncthreads();
        cur ^= 1;
    }

    // ---- epilogue: add b1, write hbuf, fp64 per-block BN partials ----
    float b1c[8];
#pragma unroll
    for (int j = 0; j < 8; ++j) b1c[j] = b1[d0 + tx + 16 * j];

    double sd[8], sq[8];
#pragma unroll
    for (int j = 0; j < 8; ++j) { sd[j] = 0.0; sq[j] = 0.0; }

#pragma unroll
    for (int i = 0; i < 8; ++i) {
        float* op = hbuf + ((size_t)(R + ty * 8 + i)) * D_ + d0 + tx;
#pragma unroll
        for (int j = 0; j < 8; ++j) {
            const float hf = acc[i][j] + b1c[j];
            op[16 * j] = hf;
            const double dh = (double)hf;
            sd[j] += dh;
            sq[j] = fma(dh, dh, sq[j]);
        }
    }

    // reduce over ty within wave (lane bits 4,5)
#pragma unroll
    for (int j = 0; j < 8; ++j) {
        sd[j] += __shfl_xor(sd[j], 16); sd[j] += __shfl_xor(sd[j], 32);
        sq[j] += __shfl_xor(sq[j], 16); sq[j] += __shfl_xor(sq[j], 32);
    }

    double* dsh = (double*)&As[0][0];   // reuse LDS (8 KB needed, 17.4 KB avail)
    const int wv = tid >> 6;
    const int lane = tid & 63;
    __syncthreads();
    if (lane < 16) {
#pragma unroll
        for (int j = 0; j < 8; ++j) {
            dsh[((wv * 16 + lane) * 8 + j) * 2 + 0] = sd[j];
            dsh[((wv * 16 + lane) * 8 + j) * 2 + 1] = sq[j];
        }
    }
    __syncthreads();
    if (tid < 128) {
        const int tx2 = tid & 15;
        const int j2 = tid >> 4;
        double S = 0.0, Q = 0.0;
#pragma unroll
        for (int w = 0; w < 4; ++w) {
            S += dsh[((w * 16 + tx2) * 8 + j2) * 2 + 0];
            Q += dsh[((w * 16 + tx2) * 8 + j2) * 2 + 1];
        }
        const int col = d0 + tx2 + 16 * j2;
        const int bt = b_base >> 7;
        pSum[((size_t)(bt * Tc + tc)) * D_ + col] = S;
        pSq [((size_t)(bt * Tc + tc)) * D_ + col] = Q;
    }
}

// ---------------- finalize: 4 partials -> scale/shift (fp64, deterministic)
__global__ __launch_bounds__(256)
void finalize_kernel(const double* __restrict__ pSum, const double* __restrict__ pSq,
                     const float* __restrict__ gamma, const float* __restrict__ bn_beta,
                     float* __restrict__ scaleArr, float* __restrict__ shiftArr, int Tc)
{
    const int tc = blockIdx.x;
    const int d = blockIdx.y * 256 + threadIdx.x;
    double S = 0.0, Q = 0.0;
#pragma unroll
    for (int bt = 0; bt < 4; ++bt) {
        S += pSum[((size_t)(bt * Tc + tc)) * D_ + d];
        Q += pSq [((size_t)(bt * Tc + tc)) * D_ + d];
    }
    const double mean = S / (double)B_;
    const double var  = Q / (double)B_ - mean * mean;
    const double rs   = 1.0 / sqrt(var + 1e-5);
    const double g    = (double)gamma[d] * rs;
    scaleArr[tc * D_ + d] = (float)g;
    shiftArr[tc * D_ + d] = (float)((double)bn_beta[d] - g * mean);
}

// ---------------- Scan: per-batch-row recurrence with next-step prefetch
__global__ __launch_bounds__(128)
void scan_kernel(const float* __restrict__ hbuf, const float* __restrict__ scaleArr,
                 const float* __restrict__ shiftArr, const float* __restrict__ W2,
                 const float* __restrict__ b2, float* __restrict__ out,
                 float* __restrict__ sMem1, float* __restrict__ sSpk1,
                 float* __restrict__ sMem2, float* __restrict__ sSpk2,
                 int t0, int Tc)
{
    const int b   = blockIdx.x;
    const int tid = threadIdx.x;
    const int d0  = tid * 4;
    const int wv  = tid >> 6;
    const int lane = tid & 63;

    float4 m1, s1;
    float mem2[O_], spk2[O_];
    if (t0 == 0) {
        m1 = make_float4(0.f, 0.f, 0.f, 0.f);
        s1 = make_float4(0.f, 0.f, 0.f, 0.f);
#pragma unroll
        for (int o = 0; o < O_; ++o) { mem2[o] = 0.f; spk2[o] = 0.f; }
    } else {
        m1 = *(const float4*)(sMem1 + (size_t)b * D_ + d0);
        s1 = *(const float4*)(sSpk1 + (size_t)b * D_ + d0);
#pragma unroll
        for (int o = 0; o < O_; ++o) { mem2[o] = sMem2[b * O_ + o]; spk2[o] = sSpk2[b * O_ + o]; }
    }

    float4 w2v[O_];
    float b2v[O_];
#pragma unroll
    for (int o = 0; o < O_; ++o) {
        w2v[o] = *(const float4*)(W2 + o * D_ + d0);
        b2v[o] = b2[o];
    }

    __shared__ float red[2][2][O_];

    float4 hv = *(const float4*)(hbuf + ((size_t)0 * B_ + b) * D_ + d0);
    float4 sc = *(const float4*)(scaleArr + 0 * D_ + d0);
    float4 sf = *(const float4*)(shiftArr + 0 * D_ + d0);

    for (int tc = 0; tc < Tc; ++tc) {
        const int par = tc & 1;

        // prefetch next step while this step's serial chain runs
        float4 hvN, scN, sfN;
        if (tc + 1 < Tc) {
            hvN = *(const float4*)(hbuf + ((size_t)(tc + 1) * B_ + b) * D_ + d0);
            scN = *(const float4*)(scaleArr + (tc + 1) * D_ + d0);
            sfN = *(const float4*)(shiftArr + (tc + 1) * D_ + d0);
        }

        float4 cur1;
        cur1.x = fmaf(sc.x, hv.x, sf.x);
        cur1.y = fmaf(sc.y, hv.y, sf.y);
        cur1.z = fmaf(sc.z, hv.z, sf.z);
        cur1.w = fmaf(sc.w, hv.w, sf.w);

        m1.x = fmaf(0.5f, m1.x, cur1.x) - s1.x;
        m1.y = fmaf(0.5f, m1.y, cur1.y) - s1.y;
        m1.z = fmaf(0.5f, m1.z, cur1.z) - s1.z;
        m1.w = fmaf(0.5f, m1.w, cur1.w) - s1.w;

        s1.x = ((m1.x - 1.0f) > 0.f) ? 1.f : 0.f;
        s1.y = ((m1.y - 1.0f) > 0.f) ? 1.f : 0.f;
        s1.z = ((m1.z - 1.0f) > 0.f) ? 1.f : 0.f;
        s1.w = ((m1.w - 1.0f) > 0.f) ? 1.f : 0.f;

        float p[O_];
#pragma unroll
        for (int o = 0; o < O_; ++o) {
            float v;
            v = s1.x * w2v[o].x;
            v = fmaf(s1.y, w2v[o].y, v);
            v = fmaf(s1.z, w2v[o].z, v);
            v = fmaf(s1.w, w2v[o].w, v);
            p[o] = v;
        }
#pragma unroll
        for (int o = 0; o < O_; ++o) {
#pragma unroll
            for (int off = 32; off > 0; off >>= 1)
                p[o] += __shfl_xor(p[o], off);
        }
        if (lane == 0) {
#pragma unroll
            for (int o = 0; o < O_; ++o) red[par][wv][o] = p[o];
        }
        __syncthreads();
#pragma unroll
        for (int o = 0; o < O_; ++o) {
            const float cur2 = red[par][0][o] + red[par][1][o] + b2v[o];
            mem2[o] = fmaf(0.5f, mem2[o], cur2) - spk2[o];
            spk2[o] = ((mem2[o] - 1.0f) > 0.f) ? 1.f : 0.f;
        }
        if (tid < O_)
            out[((size_t)(t0 + tc) * B_ + b) * O_ + tid] = spk2[tid];

        hv = hvN; sc = scN; sf = sfN;
    }

    *(float4*)(sMem1 + (size_t)b * D_ + d0) = m1;
    *(float4*)(sSpk1 + (size_t)b * D_ + d0) = s1;
    if (tid < O_) {
        sMem2[b * O_ + tid] = mem2[tid];
        sSpk2[b * O_ + tid] = spk2[tid];
    }
}

extern "C" void kernel_launch(void* const* d_in, const int* in_sizes, int n_in,
                              void* d_out, int out_size, void* d_ws, size_t ws_size,
                              hipStream_t stream) {
    const float* data    = (const float*)d_in[0];
    const float* drop    = (const float*)d_in[1];
    const float* W1      = (const float*)d_in[2];
    const float* b1      = (const float*)d_in[3];
    const float* gamma   = (const float*)d_in[4];
    const float* bn_beta = (const float*)d_in[5];
    const float* W2      = (const float*)d_in[6];
    const float* b2      = (const float*)d_in[7];
    float* out = (float*)d_out;

    const size_t stateBytes = ((size_t)2 * B_ * D_ + (size_t)2 * B_ * O_) * 4;
    int Tc = T_;
    while (Tc > 1) {
        // hbuf + scale/shift + pSum/pSq(double,4 tiles)
        const size_t need = (size_t)Tc * B_ * D_ * 4 + (size_t)Tc * D_ * 8
                          + (size_t)8 * Tc * D_ * 8 + stateBytes;
        if (need <= ws_size) break;
        Tc >>= 1;
    }

    char* p = (char*)d_ws;
    double* pSum    = (double*)p; p += (size_t)4 * Tc * D_ * 8;
    double* pSq     = (double*)p; p += (size_t)4 * Tc * D_ * 8;
    float* hbuf     = (float*)p; p += (size_t)Tc * B_ * D_ * 4;
    float* scaleArr = (float*)p; p += (size_t)Tc * D_ * 4;
    float* shiftArr = (float*)p; p += (size_t)Tc * D_ * 4;
    float* sMem1    = (float*)p; p += (size_t)B_ * D_ * 4;
    float* sSpk1    = (float*)p; p += (size_t)B_ * D_ * 4;
    float* sMem2    = (float*)p; p += (size_t)B_ * O_ * 4;
    float* sSpk2    = (float*)p; p += (size_t)B_ * O_ * 4;

    const int numX = (Tc * B_) / BM;
    for (int t0 = 0; t0 < T_; t0 += Tc) {
        gemm1_kernel<<<numX * (D_ / BN), 256, 0, stream>>>(
            data, drop, W1, b1, hbuf, pSum, pSq, t0, Tc, numX);
        finalize_kernel<<<dim3(Tc, D_ / 256), 256, 0, stream>>>(
            pSum, pSq, gamma, bn_beta, scaleArr, shiftArr, Tc);
        scan_kernel<<<B_, 128, 0, stream>>>(hbuf, scaleArr, shiftArr, W2, b2, out,
                                            sMem1, sSpk1, sMem2, sSpk2, t0, Tc);
    }
}

// Round 3
// 908.815 us; speedup vs baseline: 3.0221x; 3.0221x over previous
//
#include <hip/hip_runtime.h>
#include <math.h>

#define B_ 512
#define T_ 128
#define D_ 512
#define O_ 10

// ---------------- GEMM1 + fused BN partial stats ----------------
#define BM 128
#define BN 128
#define BK 16
#define LR 17   // LDS row stride: row-group stride 8*17=136 ≡ 8 banks (A conflict-free);
                // W columns interleaved (tx + 16*j): tx-stride 17 banks, odd → conflict-free
                // [verified R2: SQ_LDS_BANK_CONFLICT 2.43e8 -> 9.5e6]

// NOTE: no min-waves clause — __launch_bounds__(256,2) capped VGPR at 128 and
// spilled the accumulators in-loop (R2: 6.5 GB scratch writes). Single-buffer
// loop fits at ~108 VGPR.
__global__ __launch_bounds__(256)
void gemm1_kernel(const float* __restrict__ data, const float* __restrict__ drop,
                  const float* __restrict__ W1, const float* __restrict__ b1,
                  float* __restrict__ hbuf, double* __restrict__ pSum,
                  double* __restrict__ pSq, int t0, int Tc, int numX)
{
    __shared__ float As[BM * LR];
    __shared__ float Ws[BN * LR];

    const int tid = threadIdx.x;
    const int bid = blockIdx.x;

    // XCD swizzle: the 4 d-tiles sharing one A-slab land on the same XCD.
    int g, yy;
    if (numX & 7) { g = bid >> 2; yy = bid & 3; }
    else {
        const int xcd = bid & 7;
        const int rest = bid >> 3;
        yy = rest & 3;
        g = (rest >> 2) * 8 + xcd;
    }
    const int R = g * BM;          // chunk-row base (tc*512 + b_base)
    const int tc = R >> 9;
    const int b_base = R & 511;
    const int t = t0 + tc;
    const int d0 = yy * BN;

    const int tx = tid & 15;       // col group: cols tx + 16*j
    const int ty = tid >> 4;       // row group: rows ty*8 + i

    float acc[8][8];
#pragma unroll
    for (int i = 0; i < 8; ++i)
#pragma unroll
        for (int j = 0; j < 8; ++j) acc[i][j] = 0.f;

    const int lm0 = tid >> 2;          // 0..63
    const int lk0 = (tid & 3) * 4;     // 0,4,8,12
    const float* dataRow = data + ((size_t)b_base * T_ + t) * D_;
    const float* dropRow = drop + ((size_t)t * B_ + b_base) * D_;
    const float* WRow    = W1 + (size_t)d0 * D_;

    for (int k0 = 0; k0 < D_; k0 += BK) {
#pragma unroll
        for (int half = 0; half < 2; ++half) {
            const int m = lm0 + half * 64;
            const float4 dv = *(const float4*)(dataRow + (size_t)m * T_ * D_ + k0 + lk0);
            const float4 mv = *(const float4*)(dropRow + (size_t)m * D_ + k0 + lk0);
            float4 av;
            av.x = dv.x * mv.x; av.y = dv.y * mv.y;
            av.z = dv.z * mv.z; av.w = dv.w * mv.w;
            *(float4*)(&As[m * LR + lk0]) = av;
            const float4 wv = *(const float4*)(WRow + (size_t)m * D_ + k0 + lk0);
            *(float4*)(&Ws[m * LR + lk0]) = wv;
        }
        __syncthreads();
#pragma unroll
        for (int kk = 0; kk < BK; kk += 4) {
            float4 a[8], w[8];
#pragma unroll
            for (int i = 0; i < 8; ++i)
                a[i] = *(const float4*)(&As[(ty * 8 + i) * LR + kk]);
#pragma unroll
            for (int j = 0; j < 8; ++j)
                w[j] = *(const float4*)(&Ws[(tx + 16 * j) * LR + kk]);
#pragma unroll
            for (int i = 0; i < 8; ++i)
#pragma unroll
                for (int j = 0; j < 8; ++j) {
                    acc[i][j] = fmaf(a[i].x, w[j].x, acc[i][j]);
                    acc[i][j] = fmaf(a[i].y, w[j].y, acc[i][j]);
                    acc[i][j] = fmaf(a[i].z, w[j].z, acc[i][j]);
                    acc[i][j] = fmaf(a[i].w, w[j].w, acc[i][j]);
                }
        }
        __syncthreads();
    }

    // ---- epilogue: add b1, write hbuf, fp64 per-block BN partials ----
    float b1c[8];
#pragma unroll
    for (int j = 0; j < 8; ++j) b1c[j] = b1[d0 + tx + 16 * j];

    double sd[8], sq[8];
#pragma unroll
    for (int j = 0; j < 8; ++j) { sd[j] = 0.0; sq[j] = 0.0; }

#pragma unroll
    for (int i = 0; i < 8; ++i) {
        float* op = hbuf + ((size_t)(R + ty * 8 + i)) * D_ + d0 + tx;
#pragma unroll
        for (int j = 0; j < 8; ++j) {
            const float hf = acc[i][j] + b1c[j];
            op[16 * j] = hf;
            const double dh = (double)hf;
            sd[j] += dh;
            sq[j] = fma(dh, dh, sq[j]);
        }
    }

    // reduce over ty within wave (lane bits 4,5)
#pragma unroll
    for (int j = 0; j < 8; ++j) {
        sd[j] += __shfl_xor(sd[j], 16); sd[j] += __shfl_xor(sd[j], 32);
        sq[j] += __shfl_xor(sq[j], 16); sq[j] += __shfl_xor(sq[j], 32);
    }

    double* dsh = (double*)&As[0];   // reuse LDS (8 KB needed, 8.7 KB in As)
    const int wv = tid >> 6;
    const int lane = tid & 63;
    __syncthreads();
    if (lane < 16) {
#pragma unroll
        for (int j = 0; j < 8; ++j) {
            dsh[((wv * 16 + lane) * 8 + j) * 2 + 0] = sd[j];
            dsh[((wv * 16 + lane) * 8 + j) * 2 + 1] = sq[j];
        }
    }
    __syncthreads();
    if (tid < 128) {
        const int tx2 = tid & 15;
        const int j2 = tid >> 4;
        double S = 0.0, Q = 0.0;
#pragma unroll
        for (int w = 0; w < 4; ++w) {
            S += dsh[((w * 16 + tx2) * 8 + j2) * 2 + 0];
            Q += dsh[((w * 16 + tx2) * 8 + j2) * 2 + 1];
        }
        const int col = d0 + tx2 + 16 * j2;
        const int bt = b_base >> 7;
        pSum[((size_t)(bt * Tc + tc)) * D_ + col] = S;
        pSq [((size_t)(bt * Tc + tc)) * D_ + col] = Q;
    }
}

// ---------------- finalize: 4 partials -> scale/shift (fp64, deterministic)
__global__ __launch_bounds__(256)
void finalize_kernel(const double* __restrict__ pSum, const double* __restrict__ pSq,
                     const float* __restrict__ gamma, const float* __restrict__ bn_beta,
                     float* __restrict__ scaleArr, float* __restrict__ shiftArr, int Tc)
{
    const int tc = blockIdx.x;
    const int d = blockIdx.y * 256 + threadIdx.x;
    double S = 0.0, Q = 0.0;
#pragma unroll
    for (int bt = 0; bt < 4; ++bt) {
        S += pSum[((size_t)(bt * Tc + tc)) * D_ + d];
        Q += pSq [((size_t)(bt * Tc + tc)) * D_ + d];
    }
    const double mean = S / (double)B_;
    const double var  = Q / (double)B_ - mean * mean;
    const double rs   = 1.0 / sqrt(var + 1e-5);
    const double g    = (double)gamma[d] * rs;
    scaleArr[tc * D_ + d] = (float)g;
    shiftArr[tc * D_ + d] = (float)((double)bn_beta[d] - g * mean);
}

// ---------------- Scan: per-batch-row recurrence with next-step prefetch
__global__ __launch_bounds__(128)
void scan_kernel(const float* __restrict__ hbuf, const float* __restrict__ scaleArr,
                 const float* __restrict__ shiftArr, const float* __restrict__ W2,
                 const float* __restrict__ b2, float* __restrict__ out,
                 float* __restrict__ sMem1, float* __restrict__ sSpk1,
                 float* __restrict__ sMem2, float* __restrict__ sSpk2,
                 int t0, int Tc)
{
    const int b   = blockIdx.x;
    const int tid = threadIdx.x;
    const int d0  = tid * 4;
    const int wv  = tid >> 6;
    const int lane = tid & 63;

    float4 m1, s1;
    float mem2[O_], spk2[O_];
    if (t0 == 0) {
        m1 = make_float4(0.f, 0.f, 0.f, 0.f);
        s1 = make_float4(0.f, 0.f, 0.f, 0.f);
#pragma unroll
        for (int o = 0; o < O_; ++o) { mem2[o] = 0.f; spk2[o] = 0.f; }
    } else {
        m1 = *(const float4*)(sMem1 + (size_t)b * D_ + d0);
        s1 = *(const float4*)(sSpk1 + (size_t)b * D_ + d0);
#pragma unroll
        for (int o = 0; o < O_; ++o) { mem2[o] = sMem2[b * O_ + o]; spk2[o] = sSpk2[b * O_ + o]; }
    }

    float4 w2v[O_];
    float b2v[O_];
#pragma unroll
    for (int o = 0; o < O_; ++o) {
        w2v[o] = *(const float4*)(W2 + o * D_ + d0);
        b2v[o] = b2[o];
    }

    __shared__ float red[2][2][O_];

    float4 hv = *(const float4*)(hbuf + ((size_t)0 * B_ + b) * D_ + d0);
    float4 sc = *(const float4*)(scaleArr + 0 * D_ + d0);
    float4 sf = *(const float4*)(shiftArr + 0 * D_ + d0);

    for (int tc = 0; tc < Tc; ++tc) {
        const int par = tc & 1;

        // prefetch next step while this step's serial chain runs
        float4 hvN, scN, sfN;
        if (tc + 1 < Tc) {
            hvN = *(const float4*)(hbuf + ((size_t)(tc + 1) * B_ + b) * D_ + d0);
            scN = *(const float4*)(scaleArr + (tc + 1) * D_ + d0);
            sfN = *(const float4*)(shiftArr + (tc + 1) * D_ + d0);
        }

        float4 cur1;
        cur1.x = fmaf(sc.x, hv.x, sf.x);
        cur1.y = fmaf(sc.y, hv.y, sf.y);
        cur1.z = fmaf(sc.z, hv.z, sf.z);
        cur1.w = fmaf(sc.w, hv.w, sf.w);

        m1.x = fmaf(0.5f, m1.x, cur1.x) - s1.x;
        m1.y = fmaf(0.5f, m1.y, cur1.y) - s1.y;
        m1.z = fmaf(0.5f, m1.z, cur1.z) - s1.z;
        m1.w = fmaf(0.5f, m1.w, cur1.w) - s1.w;

        s1.x = ((m1.x - 1.0f) > 0.f) ? 1.f : 0.f;
        s1.y = ((m1.y - 1.0f) > 0.f) ? 1.f : 0.f;
        s1.z = ((m1.z - 1.0f) > 0.f) ? 1.f : 0.f;
        s1.w = ((m1.w - 1.0f) > 0.f) ? 1.f : 0.f;

        float p[O_];
#pragma unroll
        for (int o = 0; o < O_; ++o) {
            float v;
            v = s1.x * w2v[o].x;
            v = fmaf(s1.y, w2v[o].y, v);
            v = fmaf(s1.z, w2v[o].z, v);
            v = fmaf(s1.w, w2v[o].w, v);
            p[o] = v;
        }
#pragma unroll
        for (int o = 0; o < O_; ++o) {
#pragma unroll
            for (int off = 32; off > 0; off >>= 1)
                p[o] += __shfl_xor(p[o], off);
        }
        if (lane == 0) {
#pragma unroll
            for (int o = 0; o < O_; ++o) red[par][wv][o] = p[o];
        }
        __syncthreads();
#pragma unroll
        for (int o = 0; o < O_; ++o) {
            const float cur2 = red[par][0][o] + red[par][1][o] + b2v[o];
            mem2[o] = fmaf(0.5f, mem2[o], cur2) - spk2[o];
            spk2[o] = ((mem2[o] - 1.0f) > 0.f) ? 1.f : 0.f;
        }
        if (tid < O_)
            out[((size_t)(t0 + tc) * B_ + b) * O_ + tid] = spk2[tid];

        hv = hvN; sc = scN; sf = sfN;
    }

    *(float4*)(sMem1 + (size_t)b * D_ + d0) = m1;
    *(float4*)(sSpk1 + (size_t)b * D_ + d0) = s1;
    if (tid < O_) {
        sMem2[b * O_ + tid] = mem2[tid];
        sSpk2[b * O_ + tid] = spk2[tid];
    }
}

extern "C" void kernel_launch(void* const* d_in, const int* in_sizes, int n_in,
                              void* d_out, int out_size, void* d_ws, size_t ws_size,
                              hipStream_t stream) {
    const float* data    = (const float*)d_in[0];
    const float* drop    = (const float*)d_in[1];
    const float* W1      = (const float*)d_in[2];
    const float* b1      = (const float*)d_in[3];
    const float* gamma   = (const float*)d_in[4];
    const float* bn_beta = (const float*)d_in[5];
    const float* W2      = (const float*)d_in[6];
    const float* b2      = (const float*)d_in[7];
    float* out = (float*)d_out;

    const size_t stateBytes = ((size_t)2 * B_ * D_ + (size_t)2 * B_ * O_) * 4;
    int Tc = T_;
    while (Tc > 1) {
        const size_t need = (size_t)Tc * B_ * D_ * 4 + (size_t)Tc * D_ * 8
                          + (size_t)8 * Tc * D_ * 8 + stateBytes;
        if (need <= ws_size) break;
        Tc >>= 1;
    }

    char* p = (char*)d_ws;
    double* pSum    = (double*)p; p += (size_t)4 * Tc * D_ * 8;
    double* pSq     = (double*)p; p += (size_t)4 * Tc * D_ * 8;
    float* hbuf     = (float*)p; p += (size_t)Tc * B_ * D_ * 4;
    float* scaleArr = (float*)p; p += (size_t)Tc * D_ * 4;
    float* shiftArr = (float*)p; p += (size_t)Tc * D_ * 4;
    float* sMem1    = (float*)p; p += (size_t)B_ * D_ * 4;
    float* sSpk1    = (float*)p; p += (size_t)B_ * D_ * 4;
    float* sMem2    = (float*)p; p += (size_t)B_ * O_ * 4;
    float* sSpk2    = (float*)p; p += (size_t)B_ * O_ * 4;

    const int numX = (Tc * B_) / BM;
    for (int t0 = 0; t0 < T_; t0 += Tc) {
        gemm1_kernel<<<numX * (D_ / BN), 256, 0, stream>>>(
            data, drop, W1, b1, hbuf, pSum, pSq, t0, Tc, numX);
        finalize_kernel<<<dim3(Tc, D_ / 256), 256, 0, stream>>>(
            pSum, pSq, gamma, bn_beta, scaleArr, shiftArr, Tc);
        scan_kernel<<<B_, 128, 0, stream>>>(hbuf, scaleArr, shiftArr, W2, b2, out,
                                            sMem1, sSpk1, sMem2, sSpk2, t0, Tc);
    }
}

// Round 4
// 552.511 us; speedup vs baseline: 4.9710x; 1.6449x over previous
//
#include <hip/hip_runtime.h>
#include <math.h>

#define B_ 512
#define T_ 128
#define D_ 512
#define O_ 10

typedef unsigned int uint32;
typedef short bf16x8 __attribute__((ext_vector_type(8)));   // 8 bf16 = 4 VGPRs (guide §3)
typedef float f32x4 __attribute__((ext_vector_type(4)));

// RNE float->bf16 (bit-exact, deterministic; any deterministic rounding keeps the
// 3-way split valid since residuals are computed exactly in fp32)
__device__ __forceinline__ uint32 bf16rne(float f) {
    uint32 u = __float_as_uint(f);
    return (u + 0x7FFFu + ((u >> 16) & 1u)) >> 16;
}
__device__ __forceinline__ float bf16f(uint32 h) { return __uint_as_float(h << 16); }

// ---------------- pre-split W1 into 3 bf16 planes [3][512][512] ----------------
__global__ __launch_bounds__(256)
void presplitW_kernel(const float* __restrict__ W1, unsigned short* __restrict__ Wsp)
{
    const int idx = blockIdx.x * 256 + threadIdx.x;   // 65536 threads, 4 elems each
    const float4 v = *(const float4*)(W1 + (size_t)idx * 4);
    float vv[4] = {v.x, v.y, v.z, v.w};
    uint32 c0[4], c1[4], c2[4];
#pragma unroll
    for (int i = 0; i < 4; ++i) {
        c0[i] = bf16rne(vv[i]);
        float r = vv[i] - bf16f(c0[i]);
        c1[i] = bf16rne(r);
        float r2 = r - bf16f(c1[i]);
        c2[i] = bf16rne(r2);
    }
    const size_t base = (size_t)idx * 4;
    uint2 w;
    w.x = c0[0] | (c0[1] << 16); w.y = c0[2] | (c0[3] << 16);
    *(uint2*)(Wsp + base) = w;
    w.x = c1[0] | (c1[1] << 16); w.y = c1[2] | (c1[3] << 16);
    *(uint2*)(Wsp + 262144 + base) = w;
    w.x = c2[0] | (c2[1] << 16); w.y = c2[2] | (c2[3] << 16);
    *(uint2*)(Wsp + 524288 + base) = w;
}

// ---------------- GEMM1: bf16x3-split MFMA + fused fp64 BN partials ----------------
// 128x128 tile, BK=32, 4 waves each computing 4x4 grid of 16x16x32 MFMA tiles.
// Verified layouts: C/D col=lane&15,row=(lane>>4)*4+reg (m89/m91);
// A/B frag: lane supplies row (lane&15), k = (lane>>4)*8 + 0..7 (m92/m97 B^T lineage).
#define SPW 40            // padded LDS row stride (ushorts): 80B -> max 2-way conflict (free)
#define SPL (128*SPW)

__global__ __launch_bounds__(256)
void gemm1_kernel(const float* __restrict__ data, const float* __restrict__ drop,
                  const unsigned short* __restrict__ Wsp, const float* __restrict__ b1,
                  float* __restrict__ hbuf, double* __restrict__ pSum,
                  double* __restrict__ pSq, int t0, int Tc)
{
    __shared__ __align__(16) unsigned short As3[3 * SPL];
    __shared__ __align__(16) unsigned short Ws3[3 * SPL];

    const int tid = threadIdx.x;
    const int bid = blockIdx.x;
    // XCD swizzle: 4 d-blocks of one A-slab co-resident per XCD (verified R3: FETCH 606->159MB)
    const int xcd = bid & 7;
    const int rest = bid >> 3;
    const int yy = rest & 3;
    const int g = (rest >> 2) * 8 + xcd;

    const int R = g * 128;            // chunk-local row base = tc*512 + b_base
    const int tc = R >> 9;
    const int b_base = R & 511;
    const int t = t0 + tc;
    const int d0 = yy * 128;

    const int w = tid >> 6;
    const int lane = tid & 63;
    const int wm = w & 1, wn = w >> 1;
    const int q = lane >> 4, r16 = lane & 15;

    f32x4 acc[4][4];
#pragma unroll
    for (int i = 0; i < 4; ++i)
#pragma unroll
        for (int j = 0; j < 4; ++j) acc[i][j] = (f32x4){0.f, 0.f, 0.f, 0.f};

    for (int k0 = 0; k0 < 512; k0 += 32) {
        // ---- stage A: load fp32, mask-mul, 3-way bf16 split, write 3 LDS planes ----
#pragma unroll
        for (int i = 0; i < 2; ++i) {
            const int p = tid + i * 256;        // 0..511 = 128 rows x 4 k-groups
            const int m = p >> 2;
            const int kg = (p & 3) * 8;
            const float* dsrc = data + ((size_t)(b_base + m) * T_ + t) * D_ + k0 + kg;
            const float* msrc = drop + ((size_t)t * B_ + b_base + m) * D_ + k0 + kg;
            const float4 dv0 = *(const float4*)(dsrc);
            const float4 dv1 = *(const float4*)(dsrc + 4);
            const float4 mv0 = *(const float4*)(msrc);
            const float4 mv1 = *(const float4*)(msrc + 4);
            float vv[8] = {dv0.x*mv0.x, dv0.y*mv0.y, dv0.z*mv0.z, dv0.w*mv0.w,
                           dv1.x*mv1.x, dv1.y*mv1.y, dv1.z*mv1.z, dv1.w*mv1.w};
            uint32 u0[8], u1[8], u2[8];
#pragma unroll
            for (int e = 0; e < 8; ++e) {
                u0[e] = bf16rne(vv[e]);
                const float r = vv[e] - bf16f(u0[e]);
                u1[e] = bf16rne(r);
                const float r2 = r - bf16f(u1[e]);
                u2[e] = bf16rne(r2);
            }
            const int dst = m * SPW + kg;
            uint4 pk;
            pk.x = u0[0]|(u0[1]<<16); pk.y = u0[2]|(u0[3]<<16);
            pk.z = u0[4]|(u0[5]<<16); pk.w = u0[6]|(u0[7]<<16);
            *(uint4*)(&As3[dst]) = pk;
            pk.x = u1[0]|(u1[1]<<16); pk.y = u1[2]|(u1[3]<<16);
            pk.z = u1[4]|(u1[5]<<16); pk.w = u1[6]|(u1[7]<<16);
            *(uint4*)(&As3[SPL + dst]) = pk;
            pk.x = u2[0]|(u2[1]<<16); pk.y = u2[2]|(u2[3]<<16);
            pk.z = u2[4]|(u2[5]<<16); pk.w = u2[6]|(u2[7]<<16);
            *(uint4*)(&As3[2*SPL + dst]) = pk;
        }
        // ---- stage B: copy pre-split W1 planes ----
#pragma unroll
        for (int i = 0; i < 6; ++i) {
            const int p = tid + i * 256;        // 0..1535 = 3 planes x 128 rows x 4 groups
            const int s = p >> 9;
            const int rem = p & 511;
            const int n = rem >> 2;
            const int kg = (rem & 3) * 8;
            const uint4 pk = *(const uint4*)(Wsp + (size_t)s * 262144
                                             + (size_t)(d0 + n) * 512 + k0 + kg);
            *(uint4*)(&Ws3[s * SPL + n * SPW + kg]) = pk;
        }
        __syncthreads();

        bf16x8 af[4][3], bfr[4][3];
#pragma unroll
        for (int mt = 0; mt < 4; ++mt)
#pragma unroll
            for (int s = 0; s < 3; ++s)
                af[mt][s] = *(const bf16x8*)(&As3[s*SPL + (wm*64 + mt*16 + r16)*SPW + q*8]);
#pragma unroll
        for (int nt = 0; nt < 4; ++nt)
#pragma unroll
            for (int s = 0; s < 3; ++s)
                bfr[nt][s] = *(const bf16x8*)(&Ws3[s*SPL + (wn*64 + nt*16 + r16)*SPW + q*8]);

#define PRODUCT(SA, SB)                                                          \
        {                                                                        \
            _Pragma("unroll")                                                    \
            for (int mt = 0; mt < 4; ++mt) {                                     \
                _Pragma("unroll")                                                \
                for (int nt = 0; nt < 4; ++nt)                                   \
                    acc[mt][nt] = __builtin_amdgcn_mfma_f32_16x16x32_bf16(       \
                        af[mt][SA], bfr[nt][SB], acc[mt][nt], 0, 0, 0);          \
            }                                                                    \
        }
        PRODUCT(0, 0)
        PRODUCT(0, 1)
        PRODUCT(1, 0)
        PRODUCT(1, 1)
        PRODUCT(0, 2)
        PRODUCT(2, 0)
#undef PRODUCT
        __syncthreads();
    }

    // ---- epilogue: +b1, write hbuf, fp64 per-block BN partials ----
    float b1c[4];
#pragma unroll
    for (int nt = 0; nt < 4; ++nt) b1c[nt] = b1[d0 + wn*64 + nt*16 + r16];

    double sd[4], sq[4];
#pragma unroll
    for (int nt = 0; nt < 4; ++nt) { sd[nt] = 0.0; sq[nt] = 0.0; }

#pragma unroll
    for (int mt = 0; mt < 4; ++mt)
#pragma unroll
        for (int r = 0; r < 4; ++r) {
            const int row = R + wm*64 + mt*16 + q*4 + r;
            float* op = hbuf + (size_t)row * D_ + d0 + wn*64 + r16;
#pragma unroll
            for (int nt = 0; nt < 4; ++nt) {
                const float hf = acc[mt][nt][r] + b1c[nt];
                op[nt*16] = hf;
                const double dh = (double)hf;
                sd[nt] += dh;
                sq[nt] = fma(dh, dh, sq[nt]);
            }
        }
    // reduce over q (lane bits 4,5): each lane covers rows {mt*16+q*4+r}
#pragma unroll
    for (int nt = 0; nt < 4; ++nt) {
        sd[nt] += __shfl_xor(sd[nt], 16); sd[nt] += __shfl_xor(sd[nt], 32);
        sq[nt] += __shfl_xor(sq[nt], 16); sq[nt] += __shfl_xor(sq[nt], 32);
    }
    double* dsh = (double*)&As3[0];   // reuse LDS (4KB needed)
    __syncthreads();
    if (q == 0) {
#pragma unroll
        for (int nt = 0; nt < 4; ++nt) {
            dsh[(w*64 + nt*16 + r16)*2 + 0] = sd[nt];
            dsh[(w*64 + nt*16 + r16)*2 + 1] = sq[nt];
        }
    }
    __syncthreads();
    if (tid < 128) {
        const int col = tid;                 // block-local col
        const int gg = col >> 6, c = col & 63;
        // waves {2g (wm=0), 2g+1 (wm=1)} both cover cols gg*64..+63
        const double S = dsh[((2*gg)*64 + c)*2 + 0] + dsh[((2*gg+1)*64 + c)*2 + 0];
        const double Q = dsh[((2*gg)*64 + c)*2 + 1] + dsh[((2*gg+1)*64 + c)*2 + 1];
        const int bt = b_base >> 7;
        pSum[((size_t)(bt*Tc + tc))*D_ + d0 + col] = S;
        pSq [((size_t)(bt*Tc + tc))*D_ + d0 + col] = Q;
    }
}

// ---------------- finalize: 4 partials -> scale/shift (fp64, deterministic) ----------------
__global__ __launch_bounds__(256)
void finalize_kernel(const double* __restrict__ pSum, const double* __restrict__ pSq,
                     const float* __restrict__ gamma, const float* __restrict__ bn_beta,
                     float* __restrict__ scaleArr, float* __restrict__ shiftArr, int Tc)
{
    const int tc = blockIdx.x;
    const int d = blockIdx.y * 256 + threadIdx.x;
    double S = 0.0, Q = 0.0;
#pragma unroll
    for (int bt = 0; bt < 4; ++bt) {
        S += pSum[((size_t)(bt * Tc + tc)) * D_ + d];
        Q += pSq [((size_t)(bt * Tc + tc)) * D_ + d];
    }
    const double mean = S / (double)B_;
    const double var  = Q / (double)B_ - mean * mean;
    const double rs   = 1.0 / sqrt(var + 1e-5);
    const double gm   = (double)gamma[d] * rs;
    scaleArr[tc * D_ + d] = (float)gm;
    shiftArr[tc * D_ + d] = (float)((double)bn_beta[d] - gm * mean);
}

// ---------------- scanA: layer-1 recurrence, elementwise per (b,d) ----------------
// Bitwise-identical per-element op chain to R3's verified scan.
__global__ __launch_bounds__(256)
void scanA_kernel(const float* __restrict__ hbuf, const float* __restrict__ scaleArr,
                  const float* __restrict__ shiftArr, unsigned short* __restrict__ spk,
                  float* __restrict__ sMem1, float* __restrict__ sSpk1, int t0, int Tc)
{
    const int idx = blockIdx.x * 256 + threadIdx.x;   // 65536 threads
    const int b = idx >> 7;
    const int d0 = (idx & 127) * 4;

    float4 m1, s1;
    if (t0 == 0) {
        m1 = make_float4(0.f, 0.f, 0.f, 0.f);
        s1 = make_float4(0.f, 0.f, 0.f, 0.f);
    } else {
        m1 = *(const float4*)(sMem1 + (size_t)b * D_ + d0);
        s1 = *(const float4*)(sSpk1 + (size_t)b * D_ + d0);
    }

    float4 hv = *(const float4*)(hbuf + (size_t)b * D_ + d0);
    float4 sc = *(const float4*)(scaleArr + d0);
    float4 sf = *(const float4*)(shiftArr + d0);

    for (int tc = 0; tc < Tc; ++tc) {
        float4 hvN, scN, sfN;
        if (tc + 1 < Tc) {
            hvN = *(const float4*)(hbuf + ((size_t)(tc + 1) * B_ + b) * D_ + d0);
            scN = *(const float4*)(scaleArr + (tc + 1) * D_ + d0);
            sfN = *(const float4*)(shiftArr + (tc + 1) * D_ + d0);
        }
        float4 cur1;
        cur1.x = fmaf(sc.x, hv.x, sf.x);
        cur1.y = fmaf(sc.y, hv.y, sf.y);
        cur1.z = fmaf(sc.z, hv.z, sf.z);
        cur1.w = fmaf(sc.w, hv.w, sf.w);

        m1.x = fmaf(0.5f, m1.x, cur1.x) - s1.x;
        m1.y = fmaf(0.5f, m1.y, cur1.y) - s1.y;
        m1.z = fmaf(0.5f, m1.z, cur1.z) - s1.z;
        m1.w = fmaf(0.5f, m1.w, cur1.w) - s1.w;

        s1.x = ((m1.x - 1.0f) > 0.f) ? 1.f : 0.f;
        s1.y = ((m1.y - 1.0f) > 0.f) ? 1.f : 0.f;
        s1.z = ((m1.z - 1.0f) > 0.f) ? 1.f : 0.f;
        s1.w = ((m1.w - 1.0f) > 0.f) ? 1.f : 0.f;

        // spikes as bf16 bits: 1.0f -> 0x3F80, 0.0f -> 0 (exact)
        const uint32 ux = (s1.x == 1.f) ? 0x3F80u : 0u;
        const uint32 uy = (s1.y == 1.f) ? 0x3F80u : 0u;
        const uint32 uz = (s1.z == 1.f) ? 0x3F80u : 0u;
        const uint32 uw = (s1.w == 1.f) ? 0x3F80u : 0u;
        uint2 pk;
        pk.x = ux | (uy << 16);
        pk.y = uz | (uw << 16);
        *(uint2*)(spk + ((size_t)tc * B_ + b) * D_ + d0) = pk;

        hv = hvN; sc = scN; sf = sfN;
    }

    *(float4*)(sMem1 + (size_t)b * D_ + d0) = m1;
    *(float4*)(sSpk1 + (size_t)b * D_ + d0) = s1;
}

// ---------------- gemm2: cur2[row][o] = spk1[row]·W2[o] + b2[o], wave per row ----------------
__global__ __launch_bounds__(256)
void gemm2_kernel(const unsigned short* __restrict__ spk, const float* __restrict__ W2,
                  const float* __restrict__ b2, float* __restrict__ cur2)
{
    const int tid = threadIdx.x;
    const int w = tid >> 6, lane = tid & 63;
    const int rowBase = blockIdx.x * 64 + w * 16;

    float w2r[O_][8];
#pragma unroll
    for (int o = 0; o < O_; ++o) {
        const float4 wa = *(const float4*)(W2 + o * D_ + lane * 8);
        const float4 wb = *(const float4*)(W2 + o * D_ + lane * 8 + 4);
        w2r[o][0] = wa.x; w2r[o][1] = wa.y; w2r[o][2] = wa.z; w2r[o][3] = wa.w;
        w2r[o][4] = wb.x; w2r[o][5] = wb.y; w2r[o][6] = wb.z; w2r[o][7] = wb.w;
    }
    float b2v[O_];
#pragma unroll
    for (int o = 0; o < O_; ++o) b2v[o] = b2[o];

    for (int rr = 0; rr < 16; ++rr) {
        const int row = rowBase + rr;
        const uint4 sv = *(const uint4*)(spk + (size_t)row * D_ + lane * 8);
        float f[8];
        f[0] = bf16f(sv.x & 0xFFFFu); f[1] = bf16f(sv.x >> 16);
        f[2] = bf16f(sv.y & 0xFFFFu); f[3] = bf16f(sv.y >> 16);
        f[4] = bf16f(sv.z & 0xFFFFu); f[5] = bf16f(sv.z >> 16);
        f[6] = bf16f(sv.w & 0xFFFFu); f[7] = bf16f(sv.w >> 16);
        float p[O_];
#pragma unroll
        for (int o = 0; o < O_; ++o) {
            float v = f[0] * w2r[o][0];
#pragma unroll
            for (int j = 1; j < 8; ++j) v = fmaf(f[j], w2r[o][j], v);
            p[o] = v;
        }
#pragma unroll
        for (int o = 0; o < O_; ++o) {
#pragma unroll
            for (int off = 32; off > 0; off >>= 1)
                p[o] += __shfl_xor(p[o], off);
        }
        float outv = 0.f;
#pragma unroll
        for (int o = 0; o < O_; ++o)
            if (lane == o) outv = p[o] + b2v[o];
        if (lane < O_)
            cur2[(size_t)row * O_ + lane] = outv;
    }
}

// ---------------- scanB: layer-2 recurrence, elementwise per (b,o) ----------------
__global__ __launch_bounds__(256)
void scanB_kernel(const float* __restrict__ cur2, float* __restrict__ out,
                  float* __restrict__ sMem2, float* __restrict__ sSpk2, int t0, int Tc)
{
    const int idx = blockIdx.x * 256 + threadIdx.x;   // 0..5119 = b*O+o
    float mem2, spk2;
    if (t0 == 0) { mem2 = 0.f; spk2 = 0.f; }
    else { mem2 = sMem2[idx]; spk2 = sSpk2[idx]; }

    float v[4], vn[4];
#pragma unroll
    for (int j = 0; j < 4; ++j) v[j] = cur2[(size_t)j * (B_ * O_) + idx];

    for (int tg = 0; tg < Tc; tg += 4) {
        if (tg + 4 < Tc) {
#pragma unroll
            for (int j = 0; j < 4; ++j)
                vn[j] = cur2[(size_t)(tg + 4 + j) * (B_ * O_) + idx];
        }
#pragma unroll
        for (int j = 0; j < 4; ++j) {
            mem2 = fmaf(0.5f, mem2, v[j]) - spk2;
            spk2 = ((mem2 - 1.0f) > 0.f) ? 1.f : 0.f;
            out[(size_t)(t0 + tg + j) * (B_ * O_) + idx] = spk2;
        }
#pragma unroll
        for (int j = 0; j < 4; ++j) v[j] = vn[j];
    }
    sMem2[idx] = mem2;
    sSpk2[idx] = spk2;
}

extern "C" void kernel_launch(void* const* d_in, const int* in_sizes, int n_in,
                              void* d_out, int out_size, void* d_ws, size_t ws_size,
                              hipStream_t stream) {
    const float* data    = (const float*)d_in[0];
    const float* drop    = (const float*)d_in[1];
    const float* W1      = (const float*)d_in[2];
    const float* b1      = (const float*)d_in[3];
    const float* gamma   = (const float*)d_in[4];
    const float* bn_beta = (const float*)d_in[5];
    const float* W2      = (const float*)d_in[6];
    const float* b2      = (const float*)d_in[7];
    float* out = (float*)d_out;

    // per-t bytes: hbuf 1MB + spk 0.5MB + cur2 20KB + scale/shift 4KB + pSum/pSq 32KB
    const size_t fixedBytes = 1572864 /*Wsp*/ + 2*1048576 /*sMem1,sSpk1*/ + 2*20480 /*sMem2,sSpk2*/;
    const size_t perT = 1048576 + 524288 + 20480 + 4096 + 32768;
    int Tc = T_;
    while (Tc > 2 && fixedBytes + (size_t)Tc * perT > ws_size) Tc >>= 1;

    char* p = (char*)d_ws;
    double* pSum    = (double*)p; p += (size_t)4 * Tc * D_ * 8;
    double* pSq     = (double*)p; p += (size_t)4 * Tc * D_ * 8;
    float* hbuf     = (float*)p; p += (size_t)Tc * B_ * D_ * 4;
    float* scaleArr = (float*)p; p += (size_t)Tc * D_ * 4;
    float* shiftArr = (float*)p; p += (size_t)Tc * D_ * 4;
    float* sMem1    = (float*)p; p += (size_t)B_ * D_ * 4;
    float* sSpk1    = (float*)p; p += (size_t)B_ * D_ * 4;
    float* sMem2    = (float*)p; p += (size_t)B_ * O_ * 4;
    float* sSpk2    = (float*)p; p += (size_t)B_ * O_ * 4;
    float* cur2     = (float*)p; p += (size_t)Tc * B_ * O_ * 4;
    unsigned short* Wsp = (unsigned short*)p; p += (size_t)3 * D_ * D_ * 2;
    unsigned short* spk = (unsigned short*)p; p += (size_t)Tc * B_ * D_ * 2;

    presplitW_kernel<<<256, 256, 0, stream>>>(W1, Wsp);

    for (int t0 = 0; t0 < T_; t0 += Tc) {
        gemm1_kernel<<<Tc * 16, 256, 0, stream>>>(data, drop, Wsp, b1, hbuf,
                                                  pSum, pSq, t0, Tc);
        finalize_kernel<<<dim3(Tc, D_ / 256), 256, 0, stream>>>(
            pSum, pSq, gamma, bn_beta, scaleArr, shiftArr, Tc);
        scanA_kernel<<<256, 256, 0, stream>>>(hbuf, scaleArr, shiftArr, spk,
                                              sMem1, sSpk1, t0, Tc);
        gemm2_kernel<<<Tc * 8, 256, 0, stream>>>(spk, W2, b2, cur2);
        scanB_kernel<<<20, 256, 0, stream>>>(cur2, out, sMem2, sSpk2, t0, Tc);
    }
}